// Round 1
// baseline (377.519 us; speedup 1.0000x reference)
//
#include <hip/hip_runtime.h>

#define Bq   4
#define Lq   9216
#define DIMc 256
#define NHc  8
#define NPc  4
#define HDc  32
#define SIDEc 96

// Generic [rows x 256] @ [256 x 256] + bias GEMM.
// VOUT=true writes to [B,NH,L,HD] layout (for the gather), else row-major [rows,256].
// NOTE: X and Y may alias (mid lives in d_out): each block stages its 16 input
// rows into LDS (+barrier) before writing exactly those rows -> no hazard.
template<int ROWS, bool VOUT>
__global__ void gemm256(const float* X, const float* __restrict__ W,
                        const float* __restrict__ bias, float* Y) {
    __shared__ float xs[ROWS][DIMc];
    const int t = threadIdx.x;
    const long base_row = (long)blockIdx.x * ROWS;
    for (int r = 0; r < ROWS; ++r)
        xs[r][t] = X[(base_row + r) * DIMc + t];
    __syncthreads();

    float acc[ROWS];
#pragma unroll
    for (int r = 0; r < ROWS; ++r) acc[r] = 0.f;

    for (int k = 0; k < DIMc; ++k) {
        float w = W[k * DIMc + t];
#pragma unroll
        for (int r = 0; r < ROWS; ++r) acc[r] += xs[r][k] * w;
    }
    const float bb = bias[t];

    if (VOUT) {
        // blocks never cross a batch boundary (Lq % ROWS == 0)
        const long b = base_row / Lq;
        const long l0 = base_row % Lq;
        const int h = t >> 5, d = t & 31;
        float* yb = Y + ((b * NHc + h) * (long)Lq + l0) * HDc + d;
#pragma unroll
        for (int r = 0; r < ROWS; ++r)
            yb[(long)r * HDc] = acc[r] + bb;
    } else {
#pragma unroll
        for (int r = 0; r < ROWS; ++r)
            Y[(base_row + r) * DIMc + t] = acc[r] + bb;
    }
}

// One block per (b,l) row: offset/weight projections, softmax, bilinear gather,
// weighted sum over NP points -> mid[b,l,256] in (h*32+d) channel order.
__global__ void deform_sample(const float* __restrict__ Q,
                              const float* __restrict__ Woff, const float* __restrict__ boff,
                              const float* __restrict__ Wwt,  const float* __restrict__ bwt,
                              const float* __restrict__ vws,  float* __restrict__ mid) {
    __shared__ float qs[DIMc];
    __shared__ float offv[NHc * NPc * 2];   // 64
    __shared__ float lg[NHc * NPc];         // 32 logits
    __shared__ float wts[NHc * NPc];        // 32 softmax weights
    __shared__ int   ri0[32], ci0[32], ri1[32], ci1[32];
    __shared__ float frs[32], fcs[32];

    const int t = threadIdx.x;
    const long row = blockIdx.x;
    const int b = (int)(row / Lq);
    const int l = (int)(row % Lq);

    qs[t] = Q[row * DIMc + t];
    __syncthreads();

    if (t < 64) {
        float acc = 0.f;
        for (int k = 0; k < DIMc; ++k) acc += qs[k] * Woff[k * 64 + t];
        offv[t] = acc + boff[t];
    } else if (t < 96) {
        const int c = t - 64;
        float acc = 0.f;
        for (int k = 0; k < DIMc; ++k) acc += qs[k] * Wwt[k * 32 + c];
        lg[c] = acc + bwt[c];
    }
    __syncthreads();

    if (t < 32) {
        // (h,p) = (t>>2, t&3).  ref: x varies fast (l%96), y slow (l/96).
        const float inv = 1.0f / (SIDEc - 1);
        const float xr = (float)(l % SIDEc) * inv;
        const float yr = (float)(l / SIDEc) * inv;
        float lx = xr + offv[t * 2 + 0];     // component 0 -> rows (faithful quirk)
        float ly = yr + offv[t * 2 + 1];     // component 1 -> cols
        lx = fminf(fmaxf(lx, 0.f), 1.f);
        ly = fminf(fmaxf(ly, 0.f), 1.f);
        const float rowf = lx * (SIDEc - 1);
        const float colf = ly * (SIDEc - 1);
        const float r0 = floorf(rowf), c0 = floorf(colf);
        const int r0i = (int)r0, c0i = (int)c0;
        ri0[t] = r0i; ci0[t] = c0i;
        ri1[t] = min(r0i + 1, SIDEc - 1);
        ci1[t] = min(c0i + 1, SIDEc - 1);
        frs[t] = rowf - r0; fcs[t] = colf - c0;
    } else if (t < 40) {
        const int h = t - 32;
        float m = -1e30f;
        for (int p = 0; p < NPc; ++p) m = fmaxf(m, lg[h * NPc + p]);
        float e[NPc], s = 0.f;
        for (int p = 0; p < NPc; ++p) { e[p] = expf(lg[h * NPc + p] - m); s += e[p]; }
        const float invs = 1.f / s;
        for (int p = 0; p < NPc; ++p) wts[h * NPc + p] = e[p] * invs;
    }
    __syncthreads();

    const int h = t >> 5, d = t & 31;
    const float* vb = vws + (((long)b * NHc + h) * Lq) * HDc + d;
    float acc = 0.f;
#pragma unroll
    for (int p = 0; p < NPc; ++p) {
        const int u = h * NPc + p;
        const float fr = frs[u], fc = fcs[u];
        const int r0 = ri0[u], r1 = ri1[u], c0 = ci0[u], c1 = ci1[u];
        const float v00 = vb[(r0 * SIDEc + c0) * HDc];
        const float v01 = vb[(r0 * SIDEc + c1) * HDc];
        const float v10 = vb[(r1 * SIDEc + c0) * HDc];
        const float v11 = vb[(r1 * SIDEc + c1) * HDc];
        const float bil = v00 * (1.f - fr) * (1.f - fc)
                        + v01 * (1.f - fr) * fc
                        + v10 * fr * (1.f - fc)
                        + v11 * fr * fc;
        acc += wts[u] * bil;
    }
    mid[row * DIMc + t] = acc;
}

extern "C" void kernel_launch(void* const* d_in, const int* in_sizes, int n_in,
                              void* d_out, int out_size, void* d_ws, size_t ws_size,
                              hipStream_t stream) {
    const float* query = (const float*)d_in[0];
    // d_in[1] = key: unused by the reference
    const float* value = (const float*)d_in[2];
    const float* Wv    = (const float*)d_in[3];
    const float* bv    = (const float*)d_in[4];
    const float* Woff  = (const float*)d_in[5];
    const float* boff  = (const float*)d_in[6];
    const float* Wwt   = (const float*)d_in[7];
    const float* bwt   = (const float*)d_in[8];
    const float* Wo    = (const float*)d_in[9];
    const float* bo    = (const float*)d_in[10];

    float* out = (float*)d_out;
    float* vws = (float*)d_ws;                 // [B,NH,L,HD] = 37.75 MB
    float* mid = out;                          // aliased: safe per gemm256 note

    const int nrows = Bq * Lq;                 // 36864
    constexpr int ROWS = 16;

    gemm256<ROWS, true ><<<nrows / ROWS, 256, 0, stream>>>(value, Wv, bv, vws);
    deform_sample<<<nrows, 256, 0, stream>>>(query, Woff, boff, Wwt, bwt, vws, mid);
    gemm256<ROWS, false><<<nrows / ROWS, 256, 0, stream>>>(mid, Wo, bo, out);
}

// Round 2
// 358.997 us; speedup vs baseline: 1.0516x; 1.0516x over previous
//
#include <hip/hip_runtime.h>

#define Bq   4
#define Lq   9216
#define DIMc 256
#define NHc  8
#define NPc  4
#define HDc  32
#define SIDEc 96

// [rows x 256] @ [256 x 256] + bias.  VOUT=true -> [B,NH,L,HD] layout.
// X may alias Y (mid in d_out): block stages its rows to LDS, barrier, then
// writes exactly those rows. ROWS=32 -> 32 FMA per W-load, VALU-bound.
template<int ROWS, bool VOUT>
__global__ __launch_bounds__(256, 2) void gemm256(const float* X,
                        const float* __restrict__ W,
                        const float* __restrict__ bias, float* Y) {
    __shared__ float xs[ROWS][DIMc];
    const int t = threadIdx.x;
    const long base = (long)blockIdx.x * ROWS;

    const float4* X4 = (const float4*)(X + base * DIMc);
    float4* xs4 = (float4*)&xs[0][0];
#pragma unroll
    for (int i = 0; i < ROWS * DIMc / 4 / 256; ++i)
        xs4[t + 256 * i] = X4[t + 256 * i];
    __syncthreads();

    float acc[ROWS];
#pragma unroll
    for (int r = 0; r < ROWS; ++r) acc[r] = 0.f;

    for (int k = 0; k < DIMc; k += 4) {
        const float w0 = W[(k + 0) * DIMc + t];
        const float w1 = W[(k + 1) * DIMc + t];
        const float w2 = W[(k + 2) * DIMc + t];
        const float w3 = W[(k + 3) * DIMc + t];
#pragma unroll
        for (int r = 0; r < ROWS; ++r) {
            const float4 q = *(const float4*)&xs[r][k];
            acc[r] = fmaf(q.w, w3, fmaf(q.z, w2, fmaf(q.y, w1, fmaf(q.x, w0, acc[r]))));
        }
    }
    const float bb = bias[t];

    if (VOUT) {
        const long b  = base / Lq;              // blocks never cross batch (Lq%ROWS==0)
        const long l0 = base % Lq;
        const int h = t >> 5, d = t & 31;
        float* yb = Y + ((b * NHc + h) * (long)Lq + l0) * HDc + d;
#pragma unroll
        for (int r = 0; r < ROWS; ++r)
            yb[(long)r * HDc] = acc[r] + bb;
    } else {
#pragma unroll
        for (int r = 0; r < ROWS; ++r)
            Y[(base + r) * DIMc + t] = acc[r] + bb;
    }
}

// Fused: Q-proj (offsets+logits) -> softmax+bilinear records -> gather -> mid.
// 16 rows per block, 256 threads.
__global__ __launch_bounds__(256, 2) void deform_fused(
        const float* __restrict__ Q,
        const float* __restrict__ Woff, const float* __restrict__ boff,
        const float* __restrict__ Wwt,  const float* __restrict__ bwt,
        const float* __restrict__ vws,  float* __restrict__ mid) {
    constexpr int R = 16;
    __shared__ float4 smem4[R * DIMc / 4];   // 16 KB: Q tile, later aliased by records
    __shared__ float  prj[R][96];            // 6 KB projection outputs
    float* qs = (float*)smem4;
    int*    recI = (int*)smem4;              // [R*32] packed idx/flags (floats 0..511)
    float4* recW = smem4 + 128;              // [R*32] premult weights (floats 512..2559)

    const int t = threadIdx.x;
    const int base = blockIdx.x * R;
    const int b  = base / Lq;
    const int l0 = base % Lq;

    // ---- A: stage Q tile (float4 coalesced) ----
    const float4* Q4 = (const float4*)(Q + (long)base * DIMc);
#pragma unroll
    for (int i = 0; i < R * DIMc / 4 / 256; ++i)   // 4
        smem4[t + 256 * i] = Q4[t + 256 * i];
    __syncthreads();

    // ---- B: projections [16 rows x 96 cols] ----
    {
        const int half = t >> 7;       // 0/1 -> rows 0-7 / 8-15
        const int c = t & 127;
        if (c < 96) {
            const float* Wp; int stride; float bb;
            if (c < 64) { Wp = Woff + c;        stride = 64; bb = boff[c]; }
            else        { Wp = Wwt + (c - 64);  stride = 32; bb = bwt[c - 64]; }
            float acc[8];
#pragma unroll
            for (int rr = 0; rr < 8; ++rr) acc[rr] = 0.f;
            for (int k = 0; k < DIMc; k += 4) {
                const float w0 = Wp[(k + 0) * stride];
                const float w1 = Wp[(k + 1) * stride];
                const float w2 = Wp[(k + 2) * stride];
                const float w3 = Wp[(k + 3) * stride];
#pragma unroll
                for (int rr = 0; rr < 8; ++rr) {
                    const float4 q = *(const float4*)&qs[(half * 8 + rr) * DIMc + k];
                    acc[rr] = fmaf(q.w, w3, fmaf(q.z, w2, fmaf(q.y, w1, fmaf(q.x, w0, acc[rr]))));
                }
            }
#pragma unroll
            for (int rr = 0; rr < 8; ++rr) prj[half * 8 + rr][c] = acc[rr] + bb;
        }
    }
    __syncthreads();   // B done: qs dead, prj live; rec region may now be written

    // ---- C: per-(row,h,p) records: softmax wt premultiplied bilinear weights ----
#pragma unroll
    for (int i = 0; i < 2; ++i) {
        const int s = t + 256 * i;          // 0..511
        const int r = s >> 5, u = s & 31;
        const int h = u >> 2, p = u & 3;
        const int l = l0 + r;
        const float inv = 1.0f / (SIDEc - 1);
        const float xr = (float)(l % SIDEc) * inv;
        const float yr = (float)(l / SIDEc) * inv;

        const float lgA = prj[r][64 + h * 4 + 0];
        const float lgB = prj[r][64 + h * 4 + 1];
        const float lgC = prj[r][64 + h * 4 + 2];
        const float lgD = prj[r][64 + h * 4 + 3];
        const float m = fmaxf(fmaxf(lgA, lgB), fmaxf(lgC, lgD));
        const float sum = expf(lgA - m) + expf(lgB - m) + expf(lgC - m) + expf(lgD - m);
        const float my = prj[r][64 + h * 4 + p];
        const float wt = expf(my - m) / sum;

        const float off0 = prj[r][u * 2 + 0];
        const float off1 = prj[r][u * 2 + 1];
        const float lx = fminf(fmaxf(xr + off0, 0.f), 1.f);   // comp 0 -> rows (ref quirk)
        const float ly = fminf(fmaxf(yr + off1, 0.f), 1.f);
        const float rowf = lx * (float)(SIDEc - 1);
        const float colf = ly * (float)(SIDEc - 1);
        const float r0f = floorf(rowf), c0f = floorf(colf);
        const int r0 = (int)r0f, c0 = (int)c0f;
        const float fr = rowf - r0f, fc = colf - c0f;
        const int drow = (r0 < SIDEc - 1) ? 1 : 0;
        const int dcol = (c0 < SIDEc - 1) ? 1 : 0;
        recI[s] = (r0 * SIDEc + c0) | (drow << 16) | (dcol << 17);
        float4 w;
        w.x = wt * (1.f - fr) * (1.f - fc);
        w.y = wt * (1.f - fr) * fc;
        w.z = wt * fr * (1.f - fc);
        w.w = wt * fr * fc;
        recW[s] = w;
    }
    __syncthreads();

    // ---- D: gather + weighted sum ----
    const int h = t >> 5, d = t & 31;
    const float* vb = vws + ((long)(b * NHc + h) * Lq) * HDc + d;
#pragma unroll 2
    for (int r = 0; r < R; ++r) {
        float acc = 0.f;
#pragma unroll
        for (int p = 0; p < NPc; ++p) {
            const int    mt = recI[r * 32 + h * 4 + p];
            const float4 w  = recW[r * 32 + h * 4 + p];
            const int sl = mt & 0xFFFF;
            const int dr = (mt & 0x10000) ? SIDEc * HDc : 0;
            const int dc = (mt & 0x20000) ? HDc : 0;
            const float* pv = vb + (long)sl * HDc;
            const float v00 = pv[0];
            const float v01 = pv[dc];
            const float v10 = pv[dr];
            const float v11 = pv[dr + dc];
            acc += w.x * v00 + w.y * v01 + w.z * v10 + w.w * v11;
        }
        mid[(long)(base + r) * DIMc + t] = acc;
    }
}

extern "C" void kernel_launch(void* const* d_in, const int* in_sizes, int n_in,
                              void* d_out, int out_size, void* d_ws, size_t ws_size,
                              hipStream_t stream) {
    const float* query = (const float*)d_in[0];
    // d_in[1] = key: unused by the reference
    const float* value = (const float*)d_in[2];
    const float* Wv    = (const float*)d_in[3];
    const float* bv    = (const float*)d_in[4];
    const float* Woff  = (const float*)d_in[5];
    const float* boff  = (const float*)d_in[6];
    const float* Wwt   = (const float*)d_in[7];
    const float* bwt   = (const float*)d_in[8];
    const float* Wo    = (const float*)d_in[9];
    const float* bo    = (const float*)d_in[10];

    float* out = (float*)d_out;
    float* vws = (float*)d_ws;           // [B,NH,L,HD] = 37.75 MB
    float* mid = out;                    // aliased; safe per gemm256 note

    const int nrows = Bq * Lq;           // 36864
    constexpr int ROWS = 32;

    gemm256<ROWS, true ><<<nrows / ROWS, 256, 0, stream>>>(value, Wv, bv, vws);
    deform_fused<<<nrows / 16, 256, 0, stream>>>(query, Woff, boff, Wwt, bwt, vws, mid);
    gemm256<ROWS, false><<<nrows / ROWS, 256, 0, stream>>>(mid, Wo, bo, out);
}

// Round 3
// 174.418 us; speedup vs baseline: 2.1645x; 2.0583x over previous
//
#include <hip/hip_runtime.h>
#include <hip/hip_bf16.h>

#define Bq   4
#define Lq   9216
#define DIMc 256
#define NHc  8
#define NPc  4
#define HDc  32
#define SIDEc 96

using f32x4  = __attribute__((ext_vector_type(4))) float;
using bf16x8 = __attribute__((ext_vector_type(8))) short;   // 8 bf16 in 4 VGPRs

static __device__ __forceinline__ short f2bf(float x) {
    union { __hip_bfloat16 h; short s; } u;
    u.h = __float2bfloat16(x);
    return u.s;
}

// W[k][n] f32 -> Wt[n][k] bf16.  grid 512 (2 matrices x 256 cols), block 256.
__global__ void transpose_cvt2(const float* __restrict__ Wv, const float* __restrict__ Wo,
                               __hip_bfloat16* __restrict__ WvT, __hip_bfloat16* __restrict__ WoT) {
    const int n = blockIdx.x & 255;
    const float* W = (blockIdx.x < 256) ? Wv : Wo;
    __hip_bfloat16* T = (blockIdx.x < 256) ? WvT : WoT;
    const int k = threadIdx.x;
    T[n * 256 + k] = __float2bfloat16(W[k * 256 + n]);
}

// C[36864x256] = X[36864x256](f32) @ Wt^T (Wt is [n][k] bf16) + bias.
// BM=128 rows/block, 8 waves, wave tile 64x64, mfma_f32_16x16x32_bf16.
// VOUT=true: store bf16 to [B,NH,L,HD]; else f32 row-major (X may alias Y:
// block stages its 128 rows to LDS before any global write of those rows).
template<bool VOUT>
__global__ __launch_bounds__(512, 4) void gemm_mfma(
        const float* __restrict__ X, const short* __restrict__ WT,
        const float* __restrict__ bias,
        __hip_bfloat16* __restrict__ Yv, float* __restrict__ Yo) {
    __shared__ short As[128][264];          // bf16 bits, +8 pad -> 528B rows (2-way free)
    const int t = threadIdx.x;
    const int base = blockIdx.x * 128;

    // ---- stage A: f32 -> bf16, coalesced 1KB rows ----
    const float4* X4 = (const float4*)(X + (long)base * DIMc);
#pragma unroll
    for (int p = 0; p < 8; ++p) {
        const int r  = p * 16 + (t >> 5);
        const int k0 = (t & 31) * 8;
        const float4 a = X4[r * 64 + (k0 >> 2)];
        const float4 b = X4[r * 64 + (k0 >> 2) + 1];
        bf16x8 v;
        v[0] = f2bf(a.x); v[1] = f2bf(a.y); v[2] = f2bf(a.z); v[3] = f2bf(a.w);
        v[4] = f2bf(b.x); v[5] = f2bf(b.y); v[6] = f2bf(b.z); v[7] = f2bf(b.w);
        *(bf16x8*)&As[r][k0] = v;
    }
    __syncthreads();

    const int lane = t & 63, wid = t >> 6;
    const int wr = wid >> 2, wc = wid & 3;        // wave tile: rows wr*64, cols wc*64
    const int lr = lane & 15, lq = lane >> 4;

    f32x4 acc[4][4];
#pragma unroll
    for (int i = 0; i < 4; ++i)
#pragma unroll
        for (int j = 0; j < 4; ++j) acc[i][j] = (f32x4){0.f, 0.f, 0.f, 0.f};

#pragma unroll
    for (int ks = 0; ks < 8; ++ks) {
        const int k0 = ks * 32 + lq * 8;
        bf16x8 a[4], b[4];
#pragma unroll
        for (int i = 0; i < 4; ++i)
            a[i] = *(const bf16x8*)&As[wr * 64 + i * 16 + lr][k0];
#pragma unroll
        for (int j = 0; j < 4; ++j)
            b[j] = *(const bf16x8*)&WT[(wc * 64 + j * 16 + lr) * 256 + k0];
#pragma unroll
        for (int i = 0; i < 4; ++i)
#pragma unroll
            for (int j = 0; j < 4; ++j)
                acc[i][j] = __builtin_amdgcn_mfma_f32_16x16x32_bf16(a[i], b[j], acc[i][j], 0, 0, 0);
    }

    // ---- epilogue: C/D mapping col=lane&15, row=(lane>>4)*4+reg ----
    const int b_  = base / Lq;                    // 9216 % 128 == 0
    const int l0  = base % Lq;
#pragma unroll
    for (int i = 0; i < 4; ++i) {
        const int mrow = wr * 64 + i * 16 + lq * 4;
#pragma unroll
        for (int j = 0; j < 4; ++j) {
            const int n  = wc * 64 + j * 16 + lr;
            const float bb = bias[n];
            const f32x4 v = acc[i][j];
            if (VOUT) {
                const int h = n >> 5, d = n & 31;
                __hip_bfloat16* yb = Yv + (((long)(b_ * NHc + h)) * Lq + (l0 + mrow)) * HDc + d;
#pragma unroll
                for (int reg = 0; reg < 4; ++reg)
                    yb[(long)reg * HDc] = __float2bfloat16(v[reg] + bb);
            } else {
                float* yo = Yo + (long)(base + mrow) * DIMc + n;
#pragma unroll
                for (int reg = 0; reg < 4; ++reg)
                    yo[(long)reg * DIMc] = v[reg] + bb;
            }
        }
    }
}

// Fused: Q-proj (offsets+logits) -> softmax+bilinear records -> bf16 gather -> mid (f32).
__global__ __launch_bounds__(256, 2) void deform_fused(
        const float* __restrict__ Q,
        const float* __restrict__ Woff, const float* __restrict__ boff,
        const float* __restrict__ Wwt,  const float* __restrict__ bwt,
        const __hip_bfloat16* __restrict__ vws,  float* __restrict__ mid) {
    constexpr int R = 16;
    __shared__ float4 smem4[R * DIMc / 4];   // 16 KB: Q tile, later aliased by records
    __shared__ float  prj[R][96];            // 6 KB projection outputs
    float* qs = (float*)smem4;
    int*    recI = (int*)smem4;              // [R*32] packed idx/flags (floats 0..511)
    float4* recW = smem4 + 128;              // [R*32] premult weights (floats 512..2559)

    const int t = threadIdx.x;
    const int base = blockIdx.x * R;
    const int b  = base / Lq;
    const int l0 = base % Lq;

    // ---- A: stage Q tile ----
    const float4* Q4 = (const float4*)(Q + (long)base * DIMc);
#pragma unroll
    for (int i = 0; i < R * DIMc / 4 / 256; ++i)
        smem4[t + 256 * i] = Q4[t + 256 * i];
    __syncthreads();

    // ---- B: projections [16 rows x 96 cols] ----
    {
        const int half = t >> 7;
        const int c = t & 127;
        if (c < 96) {
            const float* Wp; int stride; float bb;
            if (c < 64) { Wp = Woff + c;        stride = 64; bb = boff[c]; }
            else        { Wp = Wwt + (c - 64);  stride = 32; bb = bwt[c - 64]; }
            float acc[8];
#pragma unroll
            for (int rr = 0; rr < 8; ++rr) acc[rr] = 0.f;
            for (int k = 0; k < DIMc; k += 4) {
                const float w0 = Wp[(k + 0) * stride];
                const float w1 = Wp[(k + 1) * stride];
                const float w2 = Wp[(k + 2) * stride];
                const float w3 = Wp[(k + 3) * stride];
#pragma unroll
                for (int rr = 0; rr < 8; ++rr) {
                    const float4 q = *(const float4*)&qs[(half * 8 + rr) * DIMc + k];
                    acc[rr] = fmaf(q.w, w3, fmaf(q.z, w2, fmaf(q.y, w1, fmaf(q.x, w0, acc[rr]))));
                }
            }
#pragma unroll
            for (int rr = 0; rr < 8; ++rr) prj[half * 8 + rr][c] = acc[rr] + bb;
        }
    }
    __syncthreads();

    // ---- C: records: softmax wt premultiplied bilinear weights ----
#pragma unroll
    for (int i = 0; i < 2; ++i) {
        const int s = t + 256 * i;
        const int r = s >> 5, u = s & 31;
        const int h = u >> 2, p = u & 3;
        const int l = l0 + r;
        const float inv = 1.0f / (SIDEc - 1);
        const float xr = (float)(l % SIDEc) * inv;
        const float yr = (float)(l / SIDEc) * inv;

        const float lgA = prj[r][64 + h * 4 + 0];
        const float lgB = prj[r][64 + h * 4 + 1];
        const float lgC = prj[r][64 + h * 4 + 2];
        const float lgD = prj[r][64 + h * 4 + 3];
        const float m = fmaxf(fmaxf(lgA, lgB), fmaxf(lgC, lgD));
        const float sum = expf(lgA - m) + expf(lgB - m) + expf(lgC - m) + expf(lgD - m);
        const float my = prj[r][64 + h * 4 + p];
        const float wt = expf(my - m) / sum;

        const float off0 = prj[r][u * 2 + 0];
        const float off1 = prj[r][u * 2 + 1];
        const float lx = fminf(fmaxf(xr + off0, 0.f), 1.f);   // comp 0 -> rows (ref quirk)
        const float ly = fminf(fmaxf(yr + off1, 0.f), 1.f);
        const float rowf = lx * (float)(SIDEc - 1);
        const float colf = ly * (float)(SIDEc - 1);
        const float r0f = floorf(rowf), c0f = floorf(colf);
        const int r0 = (int)r0f, c0 = (int)c0f;
        const float fr = rowf - r0f, fc = colf - c0f;
        const int drow = (r0 < SIDEc - 1) ? 1 : 0;
        const int dcol = (c0 < SIDEc - 1) ? 1 : 0;
        recI[s] = (r0 * SIDEc + c0) | (drow << 16) | (dcol << 17);
        float4 w;
        w.x = wt * (1.f - fr) * (1.f - fc);
        w.y = wt * (1.f - fr) * fc;
        w.z = wt * fr * (1.f - fc);
        w.w = wt * fr * fc;
        recW[s] = w;
    }
    __syncthreads();

    // ---- D: bf16 gather + weighted sum ----
    const int h = t >> 5, d = t & 31;
    const __hip_bfloat16* vb = vws + ((long)(b * NHc + h) * Lq) * HDc + d;
#pragma unroll 2
    for (int r = 0; r < R; ++r) {
        float acc = 0.f;
#pragma unroll
        for (int p = 0; p < NPc; ++p) {
            const int    mt = recI[r * 32 + h * 4 + p];
            const float4 w  = recW[r * 32 + h * 4 + p];
            const int sl = mt & 0xFFFF;
            const int dr = (mt & 0x10000) ? SIDEc * HDc : 0;
            const int dc = (mt & 0x20000) ? HDc : 0;
            const __hip_bfloat16* pv = vb + (long)sl * HDc;
            const float v00 = __bfloat162float(pv[0]);
            const float v01 = __bfloat162float(pv[dc]);
            const float v10 = __bfloat162float(pv[dr]);
            const float v11 = __bfloat162float(pv[dr + dc]);
            acc += w.x * v00 + w.y * v01 + w.z * v10 + w.w * v11;
        }
        mid[(long)(base + r) * DIMc + t] = acc;
    }
}

extern "C" void kernel_launch(void* const* d_in, const int* in_sizes, int n_in,
                              void* d_out, int out_size, void* d_ws, size_t ws_size,
                              hipStream_t stream) {
    const float* query = (const float*)d_in[0];
    // d_in[1] = key: unused by the reference
    const float* value = (const float*)d_in[2];
    const float* Wv    = (const float*)d_in[3];
    const float* bv    = (const float*)d_in[4];
    const float* Woff  = (const float*)d_in[5];
    const float* boff  = (const float*)d_in[6];
    const float* Wwt   = (const float*)d_in[7];
    const float* bwt   = (const float*)d_in[8];
    const float* Wo    = (const float*)d_in[9];
    const float* bo    = (const float*)d_in[10];

    float* out = (float*)d_out;
    char*  ws  = (char*)d_ws;
    __hip_bfloat16* vws = (__hip_bfloat16*)ws;                    // 18,874,368 B
    __hip_bfloat16* WvT = (__hip_bfloat16*)(ws + 18874368);       // 131,072 B
    __hip_bfloat16* WoT = (__hip_bfloat16*)(ws + 18874368 + 131072);
    float* mid = out;                                             // aliased; safe

    const int nrows = Bq * Lq;                                    // 36864

    transpose_cvt2<<<512, 256, 0, stream>>>(Wv, Wo, WvT, WoT);
    gemm_mfma<true ><<<nrows / 128, 512, 0, stream>>>(value, (const short*)WvT, bv, vws, nullptr);
    deform_fused<<<nrows / 16, 256, 0, stream>>>(query, Woff, boff, Wwt, bwt, vws, mid);
    gemm_mfma<false><<<nrows / 128, 512, 0, stream>>>(mid, (const short*)WoT, bo, nullptr, out);
}

// Round 4
// 132.113 us; speedup vs baseline: 2.8575x; 1.3202x over previous
//
#include <hip/hip_runtime.h>
#include <hip/hip_bf16.h>

#define Bq   4
#define Lq   9216
#define DIMc 256
#define NHc  8
#define NPc  4
#define HDc  32
#define SIDEc 96

using f32x4  = __attribute__((ext_vector_type(4))) float;
using bf16x8 = __attribute__((ext_vector_type(8))) short;
using u16x8  = __attribute__((ext_vector_type(8))) unsigned short;

static __device__ __forceinline__ short f2bf(float x) {
    union { __hip_bfloat16 h; short s; } u;
    u.h = __float2bfloat16(x);
    return u.s;
}
static __device__ __forceinline__ float bfbits(unsigned short s) {
    union { unsigned u; float f; } v; v.u = ((unsigned)s) << 16; return v.f;
}

// Build WvT/WoT ([n][k] bf16) and split-bf16 projection weights WpHi/WpLo ([96][256]).
__global__ void prep(const float* __restrict__ Wv, const float* __restrict__ Wo,
                     const float* __restrict__ Woff, const float* __restrict__ Wwt,
                     short* __restrict__ WvT, short* __restrict__ WoT,
                     short* __restrict__ WpHi, short* __restrict__ WpLo) {
    const int id = blockIdx.x, k = threadIdx.x;
    if (id < 512) {
        const int n = id & 255;
        const float* W = (id < 256) ? Wv : Wo;
        short* T = (id < 256) ? WvT : WoT;
        T[n * 256 + k] = f2bf(W[k * 256 + n]);
    } else {
        const int p = id - 512;      // 0..95
        const float x = (p < 64) ? Woff[k * 64 + p] : Wwt[k * 32 + (p - 64)];
        const short h = f2bf(x);
        WpHi[p * 256 + k] = h;
        WpLo[p * 256 + k] = f2bf(x - bfbits((unsigned short)h));
    }
}

// C = X @ Wt^T + bias.  BM=128, 8 waves, wave tile 64x64, mfma 16x16x32 bf16.
// BF16IN: X is bf16 packed per-128-row-block at Xb + blk*65536 (d_out interleave).
// VOUT: bf16 out to [B,NH,L,HD]; else f32 row-major (aliases Xb region: block
// stages its own rows to LDS before overwriting -> safe).
template<bool VOUT, bool BF16IN>
__global__ __launch_bounds__(512, 4) void gemm_mfma(
        const float* __restrict__ Xf, const short* __restrict__ Xb,
        const short* __restrict__ WT, const float* __restrict__ bias,
        __hip_bfloat16* __restrict__ Yv, float* __restrict__ Yo) {
    __shared__ short As[128][264];
    const int t = threadIdx.x;
    const int base = blockIdx.x * 128;

    if (BF16IN) {
#pragma unroll
        for (int p = 0; p < 8; ++p) {
            const int c = p * 512 + t;
            const int r = c >> 5, k0 = (c & 31) * 8;
            *(bf16x8*)&As[r][k0] = *(const bf16x8*)&Xb[(long)blockIdx.x * 65536 + r * 256 + k0];
        }
    } else {
        const float4* X4 = (const float4*)(Xf + (long)base * DIMc);
#pragma unroll
        for (int p = 0; p < 8; ++p) {
            const int r  = p * 16 + (t >> 5);
            const int k0 = (t & 31) * 8;
            const float4 a = X4[r * 64 + (k0 >> 2)];
            const float4 b = X4[r * 64 + (k0 >> 2) + 1];
            bf16x8 v;
            v[0] = f2bf(a.x); v[1] = f2bf(a.y); v[2] = f2bf(a.z); v[3] = f2bf(a.w);
            v[4] = f2bf(b.x); v[5] = f2bf(b.y); v[6] = f2bf(b.z); v[7] = f2bf(b.w);
            *(bf16x8*)&As[r][k0] = v;
        }
    }
    __syncthreads();

    const int lane = t & 63, wid = t >> 6;
    const int wr = wid >> 2, wc = wid & 3;
    const int lr = lane & 15, lq = lane >> 4;

    f32x4 acc[4][4];
#pragma unroll
    for (int i = 0; i < 4; ++i)
#pragma unroll
        for (int j = 0; j < 4; ++j) acc[i][j] = (f32x4){0.f, 0.f, 0.f, 0.f};

#pragma unroll
    for (int ks = 0; ks < 8; ++ks) {
        const int k0 = ks * 32 + lq * 8;
        bf16x8 a[4], b[4];
#pragma unroll
        for (int i = 0; i < 4; ++i)
            a[i] = *(const bf16x8*)&As[wr * 64 + i * 16 + lr][k0];
#pragma unroll
        for (int j = 0; j < 4; ++j)
            b[j] = *(const bf16x8*)&WT[(wc * 64 + j * 16 + lr) * 256 + k0];
#pragma unroll
        for (int i = 0; i < 4; ++i)
#pragma unroll
            for (int j = 0; j < 4; ++j)
                acc[i][j] = __builtin_amdgcn_mfma_f32_16x16x32_bf16(a[i], b[j], acc[i][j], 0, 0, 0);
    }

    const int b_ = base / Lq;
    const int l0 = base % Lq;
#pragma unroll
    for (int i = 0; i < 4; ++i) {
        const int mrow = wr * 64 + i * 16 + lq * 4;
#pragma unroll
        for (int j = 0; j < 4; ++j) {
            const int n  = wc * 64 + j * 16 + lr;
            const float bb = bias[n];
            const f32x4 v = acc[i][j];
            if (VOUT) {
                const int h = n >> 5, d = n & 31;
                __hip_bfloat16* yb = Yv + (((long)(b_ * NHc + h)) * Lq + (l0 + mrow)) * HDc + d;
#pragma unroll
                for (int reg = 0; reg < 4; ++reg)
                    yb[(long)reg * HDc] = __float2bfloat16(v[reg] + bb);
            } else {
                float* yo = Yo + (long)(base + mrow) * DIMc + n;
#pragma unroll
                for (int reg = 0; reg < 4; ++reg)
                    yo[(long)reg * DIMc] = v[reg] + bb;
            }
        }
    }
}

// prj[36864][96] = query @ [Woff|Wwt] + [boff|bwt] in near-fp32 precision via
// split-bf16 3-MFMA (hi*hi + hi*lo + lo*hi; dropped lo*lo ~ 2^-18 rel).
__global__ __launch_bounds__(256, 2) void proj_mfma(
        const float* __restrict__ Q,
        const short* __restrict__ WpHi, const short* __restrict__ WpLo,
        const float* __restrict__ boff, const float* __restrict__ bwt,
        float* __restrict__ prj) {
    __shared__ float Qf[64][260];
    const int t = threadIdx.x;
    const int base = blockIdx.x * 64;

    const float4* Q4 = (const float4*)(Q + (long)base * DIMc);
#pragma unroll
    for (int p = 0; p < 16; ++p) {
        const int c = p * 256 + t;
        const int r = c >> 6, kq = c & 63;
        *(float4*)&Qf[r][kq * 4] = Q4[r * 64 + kq];
    }
    __syncthreads();

    const int lane = t & 63, w = t >> 6;
    const int lr = lane & 15, lq = lane >> 4;
    const int s0 = w * 16;

    f32x4 acc[6];
#pragma unroll
    for (int j = 0; j < 6; ++j) acc[j] = (f32x4){0.f, 0.f, 0.f, 0.f};

#pragma unroll
    for (int ks = 0; ks < 8; ++ks) {
        const int k0 = ks * 32 + lq * 8;
        const float* qp = &Qf[s0 + lr][k0];
        const float4 a0 = *(const float4*)qp;
        const float4 a1 = *(const float4*)(qp + 4);
        const float xs[8] = {a0.x, a0.y, a0.z, a0.w, a1.x, a1.y, a1.z, a1.w};
        bf16x8 ah, al;
#pragma unroll
        for (int e = 0; e < 8; ++e) {
            const short h = f2bf(xs[e]);
            ah[e] = h;
            al[e] = f2bf(xs[e] - bfbits((unsigned short)h));
        }
#pragma unroll
        for (int j = 0; j < 6; ++j) {
            const bf16x8 bh = *(const bf16x8*)&WpHi[(j * 16 + lr) * 256 + k0];
            const bf16x8 bl = *(const bf16x8*)&WpLo[(j * 16 + lr) * 256 + k0];
            acc[j] = __builtin_amdgcn_mfma_f32_16x16x32_bf16(ah, bh, acc[j], 0, 0, 0);
            acc[j] = __builtin_amdgcn_mfma_f32_16x16x32_bf16(ah, bl, acc[j], 0, 0, 0);
            acc[j] = __builtin_amdgcn_mfma_f32_16x16x32_bf16(al, bh, acc[j], 0, 0, 0);
        }
    }

#pragma unroll
    for (int j = 0; j < 6; ++j) {
        const int col = j * 16 + lr;
        const float bb = (col < 64) ? boff[col] : bwt[col - 64];
#pragma unroll
        for (int reg = 0; reg < 4; ++reg) {
            const int row = s0 + lq * 4 + reg;
            prj[(long)(base + row) * 96 + col] = acc[j][reg] + bb;
        }
    }
}

// 32 rows/block: prj tile -> records (softmax*bilinear premult) -> ushort8 gather
// -> bf16 mid written into d_out interleaved per 128-row gemm2 block.
__global__ __launch_bounds__(256, 2) void deform_gather(
        const float* __restrict__ prj,
        const __hip_bfloat16* __restrict__ vws,
        __hip_bfloat16* __restrict__ midb) {
    __shared__ float  prjs[32 * 96];
    __shared__ int    recI[1024];
    __shared__ float4 recW[1024];

    const int t = threadIdx.x;
    const int base = blockIdx.x * 32;
    const int b  = base / Lq;
    const int l0 = base % Lq;

    const float4* P4 = (const float4*)(prj + (long)base * 96);
#pragma unroll
    for (int i = 0; i < 3; ++i)
        ((float4*)prjs)[t + 256 * i] = P4[t + 256 * i];
    __syncthreads();

#pragma unroll
    for (int i = 0; i < 4; ++i) {
        const int s = i * 256 + t;
        const int r = s >> 5, u = s & 31;
        const int h = u >> 2, p = u & 3;
        const int l = l0 + r;
        const float* pr = &prjs[r * 96];
        const float inv = 1.0f / (SIDEc - 1);
        const float xr = (float)(l % SIDEc) * inv;
        const float yr = (float)(l / SIDEc) * inv;

        const float4 lg = *(const float4*)&pr[64 + h * 4];
        const float m = fmaxf(fmaxf(lg.x, lg.y), fmaxf(lg.z, lg.w));
        const float e0 = expf(lg.x - m), e1 = expf(lg.y - m);
        const float e2 = expf(lg.z - m), e3 = expf(lg.w - m);
        const float sum = e0 + e1 + e2 + e3;
        const float ep = (p == 0) ? e0 : (p == 1) ? e1 : (p == 2) ? e2 : e3;
        const float wt = ep / sum;

        const float lx = fminf(fmaxf(xr + pr[u * 2 + 0], 0.f), 1.f);  // comp0->rows (ref quirk)
        const float ly = fminf(fmaxf(yr + pr[u * 2 + 1], 0.f), 1.f);
        const float rowf = lx * (float)(SIDEc - 1);
        const float colf = ly * (float)(SIDEc - 1);
        const float r0f = floorf(rowf), c0f = floorf(colf);
        const int r0 = (int)r0f, c0 = (int)c0f;
        const float fr = rowf - r0f, fc = colf - c0f;
        const int drow = (r0 < SIDEc - 1) ? 1 : 0;
        const int dcol = (c0 < SIDEc - 1) ? 1 : 0;
        recI[s] = (r0 * SIDEc + c0) | (drow << 16) | (dcol << 17);
        float4 w4;
        w4.x = wt * (1.f - fr) * (1.f - fc);
        w4.y = wt * (1.f - fr) * fc;
        w4.z = wt * fr * (1.f - fc);
        w4.w = wt * fr * fc;
        recW[s] = w4;
    }
    __syncthreads();

    // lane owns (h, 8-channel quad-pair): h=(t>>2)&7, dq=t&3; 32 lanes = 1 row.
    const int h = (t >> 2) & 7, dq = t & 3;
    const int rhalf = (t >> 5) & 1, wid = t >> 6;
    const __hip_bfloat16* vb = vws + ((long)(b * NHc + h) * Lq) * HDc + dq * 8;
    const int chan = (t & 31) * 8;

#pragma unroll
    for (int pass = 0; pass < 4; ++pass) {
        const int r = pass * 8 + wid * 2 + rhalf;
        float acc[8];
#pragma unroll
        for (int e = 0; e < 8; ++e) acc[e] = 0.f;
#pragma unroll
        for (int p = 0; p < 4; ++p) {
            const int    mt = recI[r * 32 + h * 4 + p];
            const float4 w  = recW[r * 32 + h * 4 + p];
            const int sl = mt & 0xFFFF;
            const int dr = (mt & 0x10000) ? SIDEc * HDc : 0;
            const int dc = (mt & 0x20000) ? HDc : 0;
            const __hip_bfloat16* pv = vb + (long)sl * HDc;
            const u16x8 u00 = *(const u16x8*)(pv);
            const u16x8 u01 = *(const u16x8*)(pv + dc);
            const u16x8 u10 = *(const u16x8*)(pv + dr);
            const u16x8 u11 = *(const u16x8*)(pv + dr + dc);
#pragma unroll
            for (int e = 0; e < 8; ++e)
                acc[e] += w.x * bfbits(u00[e]) + w.y * bfbits(u01[e])
                        + w.z * bfbits(u10[e]) + w.w * bfbits(u11[e]);
        }
        const int rg = base + r;
        u16x8 o;
#pragma unroll
        for (int e = 0; e < 8; ++e) o[e] = (unsigned short)f2bf(acc[e]);
        *(u16x8*)(midb + ((long)(rg >> 7) << 16) + ((rg & 127) << 8) + chan) = o;
    }
}

extern "C" void kernel_launch(void* const* d_in, const int* in_sizes, int n_in,
                              void* d_out, int out_size, void* d_ws, size_t ws_size,
                              hipStream_t stream) {
    const float* query = (const float*)d_in[0];
    // d_in[1] = key: unused by the reference
    const float* value = (const float*)d_in[2];
    const float* Wv    = (const float*)d_in[3];
    const float* bv    = (const float*)d_in[4];
    const float* Woff  = (const float*)d_in[5];
    const float* boff  = (const float*)d_in[6];
    const float* Wwt   = (const float*)d_in[7];
    const float* bwt   = (const float*)d_in[8];
    const float* Wo    = (const float*)d_in[9];
    const float* bo    = (const float*)d_in[10];

    float* out = (float*)d_out;
    char*  ws  = (char*)d_ws;
    __hip_bfloat16* vws = (__hip_bfloat16*)ws;                       // 18,874,368 B
    short* WvT  = (short*)(ws + 18874368);                           // 131,072 B
    short* WoT  = (short*)(ws + 18874368 + 131072);                  // 131,072 B
    short* WpHi = (short*)(ws + 18874368 + 262144);                  // 49,152 B
    short* WpLo = (short*)(ws + 18874368 + 262144 + 49152);          // 49,152 B
    float* prj  = (float*)(ws + 18874368 + 262144 + 98304);          // 14,155,776 B (tot ~33.4 MB)
    __hip_bfloat16* midb = (__hip_bfloat16*)d_out;                   // interleaved per 128-row block

    const int nrows = Bq * Lq;   // 36864

    prep<<<608, 256, 0, stream>>>(Wv, Wo, Woff, Wwt, WvT, WoT, WpHi, WpLo);
    gemm_mfma<true, false><<<nrows / 128, 512, 0, stream>>>(value, nullptr, WvT, bv, vws, nullptr);
    proj_mfma<<<nrows / 64, 256, 0, stream>>>(query, WpHi, WpLo, boff, bwt, prj);
    deform_gather<<<nrows / 32, 256, 0, stream>>>(prj, vws, midb);
    gemm_mfma<false, true><<<nrows / 128, 512, 0, stream>>>(nullptr, (const short*)midb, WoT, bo, nullptr, out);
}

// Round 5
// 100.199 us; speedup vs baseline: 3.7677x; 1.3185x over previous
//
#include <hip/hip_runtime.h>
#include <hip/hip_bf16.h>

#define Bq   4
#define Lq   9216
#define DIMc 256
#define NHc  8
#define NPc  4
#define HDc  32
#define SIDEc 96

using f32x4  = __attribute__((ext_vector_type(4))) float;
using bf16x8 = __attribute__((ext_vector_type(8))) short;
using u16x8  = __attribute__((ext_vector_type(8))) unsigned short;

static __device__ __forceinline__ short f2bf(float x) {
    union { __hip_bfloat16 h; short s; } u;
    u.h = __float2bfloat16(x);
    return u.s;
}
static __device__ __forceinline__ float bfbits(unsigned short s) {
    union { unsigned u; float f; } v; v.u = ((unsigned)s) << 16; return v.f;
}

// blocks 0..63: coalesced transpose Wv/Wo -> WT[n][k] bf16 (8 cols/block via LDS).
// blocks 64..159: split-bf16 projection weights WpHi/WpLo [96][256].
__global__ void prep(const float* __restrict__ Wv, const float* __restrict__ Wo,
                     const float* __restrict__ Woff, const float* __restrict__ Wwt,
                     short* __restrict__ WvT, short* __restrict__ WoT,
                     short* __restrict__ WpHi, short* __restrict__ WpLo) {
    const int id = blockIdx.x, t = threadIdx.x;
    if (id < 64) {
        __shared__ float tile[256][8];
        const float* W = (id < 32) ? Wv : Wo;
        short* T = (id < 32) ? WvT : WoT;
        const int n0 = (id & 31) * 8;
        const float4 a = *(const float4*)&W[t * 256 + n0];
        const float4 b = *(const float4*)&W[t * 256 + n0 + 4];
        tile[t][0] = a.x; tile[t][1] = a.y; tile[t][2] = a.z; tile[t][3] = a.w;
        tile[t][4] = b.x; tile[t][5] = b.y; tile[t][6] = b.z; tile[t][7] = b.w;
        __syncthreads();
        const int n = n0 + (t >> 5), kk = (t & 31) * 8;
        bf16x8 v;
#pragma unroll
        for (int e = 0; e < 8; ++e) v[e] = f2bf(tile[kk + e][t >> 5]);
        *(bf16x8*)&T[n * 256 + kk] = v;
    } else {
        const int p = id - 64;       // 0..95
        const float x = (p < 64) ? Woff[t * 64 + p] : Wwt[t * 32 + (p - 64)];
        const short h = f2bf(x);
        WpHi[p * 256 + t] = h;
        WpLo[p * 256 + t] = f2bf(x - bfbits((unsigned short)h));
    }
}

// C[36864x256] = X @ WT^T + bias.  BM=64, 4 waves, wave tile 64x64.
// BF16IN: X bf16 packed per-64-row block at Xb + blk*32768 (first half of that
// block's own f32 output region -> alias-safe after LDS stage + barrier).
// VOUT: bf16 out to [B,NH,L,HD]; else f32 row-major.
template<bool VOUT, bool BF16IN>
__global__ __launch_bounds__(256, 3) void gemm_mfma(
        const float* __restrict__ Xf, const short* Xb,
        const short* __restrict__ WT, const float* __restrict__ bias,
        __hip_bfloat16* __restrict__ Yv, float* Yo) {
    __shared__ short As[64][264];
    const int t = threadIdx.x;
    const int base = blockIdx.x * 64;

    if (BF16IN) {
#pragma unroll
        for (int p = 0; p < 8; ++p) {
            const int c = p * 256 + t;
            const int r = c >> 5, k0 = (c & 31) * 8;
            *(bf16x8*)&As[r][k0] = *(const bf16x8*)&Xb[((long)blockIdx.x << 15) + r * 256 + k0];
        }
    } else {
        const float4* X4 = (const float4*)(Xf + (long)base * DIMc);
#pragma unroll
        for (int p = 0; p < 8; ++p) {
            const int c = p * 256 + t;
            const int r = c >> 5, kq = (c & 31) * 2;
            const float4 a = X4[r * 64 + kq];
            const float4 b = X4[r * 64 + kq + 1];
            bf16x8 v;
            v[0] = f2bf(a.x); v[1] = f2bf(a.y); v[2] = f2bf(a.z); v[3] = f2bf(a.w);
            v[4] = f2bf(b.x); v[5] = f2bf(b.y); v[6] = f2bf(b.z); v[7] = f2bf(b.w);
            *(bf16x8*)&As[r][kq * 4] = v;
        }
    }
    __syncthreads();

    const int lane = t & 63, wc = t >> 6;
    const int lr = lane & 15, lq = lane >> 4;

    f32x4 acc[4][4];
#pragma unroll
    for (int i = 0; i < 4; ++i)
#pragma unroll
        for (int j = 0; j < 4; ++j) acc[i][j] = (f32x4){0.f, 0.f, 0.f, 0.f};

#pragma unroll
    for (int ks = 0; ks < 8; ++ks) {
        const int k0 = ks * 32 + lq * 8;
        bf16x8 a[4], b[4];
#pragma unroll
        for (int i = 0; i < 4; ++i)
            a[i] = *(const bf16x8*)&As[i * 16 + lr][k0];
#pragma unroll
        for (int j = 0; j < 4; ++j)
            b[j] = *(const bf16x8*)&WT[(wc * 64 + j * 16 + lr) * 256 + k0];
#pragma unroll
        for (int i = 0; i < 4; ++i)
#pragma unroll
            for (int j = 0; j < 4; ++j)
                acc[i][j] = __builtin_amdgcn_mfma_f32_16x16x32_bf16(a[i], b[j], acc[i][j], 0, 0, 0);
    }

    const int b_ = base / Lq;          // 9216 % 64 == 0
    const int l0 = base % Lq;
#pragma unroll
    for (int i = 0; i < 4; ++i) {
        const int mrow = i * 16 + lq * 4;
#pragma unroll
        for (int j = 0; j < 4; ++j) {
            const int n  = wc * 64 + j * 16 + lr;
            const float bb = bias[n];
            const f32x4 v = acc[i][j];
            if (VOUT) {
                const int h = n >> 5, d = n & 31;
                __hip_bfloat16* yb = Yv + (((long)(b_ * NHc + h)) * Lq + (l0 + mrow)) * HDc + d;
#pragma unroll
                for (int reg = 0; reg < 4; ++reg)
                    yb[(long)reg * HDc] = __float2bfloat16(v[reg] + bb);
            } else {
                float* yo = Yo + (long)(base + mrow) * DIMc + n;
#pragma unroll
                for (int reg = 0; reg < 4; ++reg)
                    yo[(long)reg * DIMc] = v[reg] + bb;
            }
        }
    }
}

// Fused: stage Q -> split-bf16 MFMA proj (96 cols) -> records -> gather -> bf16 midb.
// 32 rows/block, 256 threads, 4 waves. Grid 1152 = 8*144, XCD-swizzled.
__global__ __launch_bounds__(256, 3) void deform_fused2(
        const float* __restrict__ Q,
        const short* __restrict__ WpHi, const short* __restrict__ WpLo,
        const float* __restrict__ boff, const float* __restrict__ bwt,
        const __hip_bfloat16* __restrict__ vws,
        __hip_bfloat16* __restrict__ midb) {
    __shared__ float  Qf[32][260];        // 33,280 B; later aliased by prjs[32*96]
    __shared__ int    recI[1024];
    __shared__ float4 recW[1024];
    float* prjs = &Qf[0][0];

    const int t = threadIdx.x;
    const int bid = (int)blockIdx.x;
    const int lb = (bid & 7) * 144 + (bid >> 3);   // XCD swizzle: each XCD -> one batch
    const int base = lb * 32;
    const int b  = base / Lq;
    const int l0 = base % Lq;

    // ---- stage Q ----
    const float4* Q4 = (const float4*)(Q + (long)base * DIMc);
#pragma unroll
    for (int p = 0; p < 8; ++p) {
        const int c = p * 256 + t;
        const int r = c >> 6, kq = c & 63;
        *(float4*)&Qf[r][kq * 4] = Q4[c];
    }
    __syncthreads();

    // ---- proj: wave w -> row-tile (w&1), col-group (w>>1)*48 ----
    const int lane = t & 63, w = t >> 6;
    const int rt = w & 1, cg = w >> 1;
    const int lr = lane & 15, lq = lane >> 4;

    f32x4 pacc[3];
#pragma unroll
    for (int jj = 0; jj < 3; ++jj) pacc[jj] = (f32x4){0.f, 0.f, 0.f, 0.f};

#pragma unroll
    for (int ks = 0; ks < 8; ++ks) {
        const int k0 = ks * 32 + lq * 8;
        const float* qp = &Qf[rt * 16 + lr][k0];
        const float4 a0 = *(const float4*)qp;
        const float4 a1 = *(const float4*)(qp + 4);
        const float xs[8] = {a0.x, a0.y, a0.z, a0.w, a1.x, a1.y, a1.z, a1.w};
        bf16x8 ah, al;
#pragma unroll
        for (int e = 0; e < 8; ++e) {
            const short hh = f2bf(xs[e]);
            ah[e] = hh;
            al[e] = f2bf(xs[e] - bfbits((unsigned short)hh));
        }
#pragma unroll
        for (int jj = 0; jj < 3; ++jj) {
            const int c = cg * 48 + jj * 16 + lr;
            const bf16x8 bh = *(const bf16x8*)&WpHi[c * 256 + k0];
            const bf16x8 bl = *(const bf16x8*)&WpLo[c * 256 + k0];
            pacc[jj] = __builtin_amdgcn_mfma_f32_16x16x32_bf16(ah, bh, pacc[jj], 0, 0, 0);
            pacc[jj] = __builtin_amdgcn_mfma_f32_16x16x32_bf16(ah, bl, pacc[jj], 0, 0, 0);
            pacc[jj] = __builtin_amdgcn_mfma_f32_16x16x32_bf16(al, bh, pacc[jj], 0, 0, 0);
        }
    }
    __syncthreads();    // all Qf reads done; prjs may overwrite

#pragma unroll
    for (int jj = 0; jj < 3; ++jj) {
        const int col = cg * 48 + jj * 16 + lr;
        const float bb = (col < 64) ? boff[col] : bwt[col - 64];
#pragma unroll
        for (int reg = 0; reg < 4; ++reg) {
            const int row = rt * 16 + lq * 4 + reg;
            prjs[row * 96 + col] = pacc[jj][reg] + bb;
        }
    }
    __syncthreads();

    // ---- records: softmax wt premultiplied bilinear weights ----
#pragma unroll
    for (int i = 0; i < 4; ++i) {
        const int s = i * 256 + t;
        const int r = s >> 5, u = s & 31;
        const int h = u >> 2, p = u & 3;
        const int l = l0 + r;
        const float* pr = &prjs[r * 96];
        const float inv = 1.0f / (SIDEc - 1);
        const float xr = (float)(l % SIDEc) * inv;
        const float yr = (float)(l / SIDEc) * inv;

        const float4 lg = *(const float4*)&pr[64 + h * 4];
        const float m = fmaxf(fmaxf(lg.x, lg.y), fmaxf(lg.z, lg.w));
        const float e0 = expf(lg.x - m), e1 = expf(lg.y - m);
        const float e2 = expf(lg.z - m), e3 = expf(lg.w - m);
        const float sum = e0 + e1 + e2 + e3;
        const float ep = (p == 0) ? e0 : (p == 1) ? e1 : (p == 2) ? e2 : e3;
        const float wt = ep / sum;

        const float lx = fminf(fmaxf(xr + pr[u * 2 + 0], 0.f), 1.f);  // comp0->rows (ref quirk)
        const float ly = fminf(fmaxf(yr + pr[u * 2 + 1], 0.f), 1.f);
        const float rowf = lx * (float)(SIDEc - 1);
        const float colf = ly * (float)(SIDEc - 1);
        const float r0f = floorf(rowf), c0f = floorf(colf);
        const int r0 = (int)r0f, c0 = (int)c0f;
        const float fr = rowf - r0f, fc = colf - c0f;
        const int drow = (r0 < SIDEc - 1) ? 1 : 0;
        const int dcol = (c0 < SIDEc - 1) ? 1 : 0;
        recI[s] = (r0 * SIDEc + c0) | (drow << 16) | (dcol << 17);
        float4 w4;
        w4.x = wt * (1.f - fr) * (1.f - fc);
        w4.y = wt * (1.f - fr) * fc;
        w4.z = wt * fr * (1.f - fc);
        w4.w = wt * fr * fc;
        recW[s] = w4;
    }
    __syncthreads();

    // ---- gather: lane owns (h, 8-channel chunk); 4-lane groups read 64B/corner ----
    const int h = (t >> 2) & 7, dq = t & 3;
    const int rhalf = (t >> 5) & 1, wid = t >> 6;
    const __hip_bfloat16* vb = vws + ((long)(b * NHc + h) * Lq) * HDc + dq * 8;
    const int chan = (t & 31) * 8;

#pragma unroll
    for (int pass = 0; pass < 4; ++pass) {
        const int r = pass * 8 + wid * 2 + rhalf;
        float acc[8];
#pragma unroll
        for (int e = 0; e < 8; ++e) acc[e] = 0.f;
#pragma unroll
        for (int p = 0; p < 4; ++p) {
            const int    mt = recI[r * 32 + h * 4 + p];
            const float4 w4 = recW[r * 32 + h * 4 + p];
            const int sl = mt & 0xFFFF;
            const int dr = (mt & 0x10000) ? SIDEc * HDc : 0;
            const int dc = (mt & 0x20000) ? HDc : 0;
            const __hip_bfloat16* pv = vb + (long)sl * HDc;
            const u16x8 u00 = *(const u16x8*)(pv);
            const u16x8 u01 = *(const u16x8*)(pv + dc);
            const u16x8 u10 = *(const u16x8*)(pv + dr);
            const u16x8 u11 = *(const u16x8*)(pv + dr + dc);
#pragma unroll
            for (int e = 0; e < 8; ++e)
                acc[e] += w4.x * bfbits(u00[e]) + w4.y * bfbits(u01[e])
                        + w4.z * bfbits(u10[e]) + w4.w * bfbits(u11[e]);
        }
        const int rg = base + r;
        u16x8 o;
#pragma unroll
        for (int e = 0; e < 8; ++e) o[e] = (unsigned short)f2bf(acc[e]);
        // midb element offset: 64-row block rg>>6 at <<15 elems (= first half of
        // that gemm2 block's own f32 output region -> alias-safe)
        *(u16x8*)(midb + ((long)(rg >> 6) << 15) + ((rg & 63) << 8) + chan) = o;
    }
}

extern "C" void kernel_launch(void* const* d_in, const int* in_sizes, int n_in,
                              void* d_out, int out_size, void* d_ws, size_t ws_size,
                              hipStream_t stream) {
    const float* query = (const float*)d_in[0];
    // d_in[1] = key: unused by the reference
    const float* value = (const float*)d_in[2];
    const float* Wv    = (const float*)d_in[3];
    const float* bv    = (const float*)d_in[4];
    const float* Woff  = (const float*)d_in[5];
    const float* boff  = (const float*)d_in[6];
    const float* Wwt   = (const float*)d_in[7];
    const float* bwt   = (const float*)d_in[8];
    const float* Wo    = (const float*)d_in[9];
    const float* bo    = (const float*)d_in[10];

    float* out = (float*)d_out;
    char*  ws  = (char*)d_ws;
    __hip_bfloat16* vws = (__hip_bfloat16*)ws;                       // 18,874,368 B
    short* WvT  = (short*)(ws + 18874368);                           // 131,072 B
    short* WoT  = (short*)(ws + 18874368 + 131072);                  // 131,072 B
    short* WpHi = (short*)(ws + 18874368 + 262144);                  // 49,152 B
    short* WpLo = (short*)(ws + 18874368 + 262144 + 49152);          // 49,152 B
    __hip_bfloat16* midb = (__hip_bfloat16*)d_out;                   // interleaved per 64-row block

    const int nrows = Bq * Lq;   // 36864

    prep<<<160, 256, 0, stream>>>(Wv, Wo, Woff, Wwt, WvT, WoT, WpHi, WpLo);
    gemm_mfma<true, false><<<nrows / 64, 256, 0, stream>>>(value, nullptr, WvT, bv, vws, nullptr);
    deform_fused2<<<nrows / 32, 256, 0, stream>>>(query, WpHi, WpLo, boff, bwt, vws, midb);
    gemm_mfma<false, true><<<nrows / 64, 256, 0, stream>>>(nullptr, (const short*)midb, WoT, bo, nullptr, out);
}